// Round 2
// baseline (133.777 us; speedup 1.0000x reference)
//
#include <hip/hip_runtime.h>
#include <math.h>

#define BB 4
#define CC 32
#define HH 128
#define WW 128

// ---------------------------------------------------------------------------
// Kernel 1: fused maxpool: x (B,C,128,128) -> p1 (B,C,64,64), p2 (B,C,32,32)
// ---------------------------------------------------------------------------
__global__ __launch_bounds__(256) void pool_kernel(const float* __restrict__ x,
                                                   float* __restrict__ p1,
                                                   float* __restrict__ p2) {
  int idx = blockIdx.x * 256 + threadIdx.x;          // B*C*32*32 = 131072
  int j  = idx & 31;
  int i  = (idx >> 5) & 31;
  int bc = idx >> 10;
  const float* xp = x + ((size_t)bc * HH + 4 * i) * WW + 4 * j;
  float4 r0 = *(const float4*)(xp);
  float4 r1 = *(const float4*)(xp + WW);
  float4 r2 = *(const float4*)(xp + 2 * WW);
  float4 r3 = *(const float4*)(xp + 3 * WW);
  float m00 = fmaxf(fmaxf(r0.x, r1.x), fmaxf(r0.y, r1.y));
  float m01 = fmaxf(fmaxf(r0.z, r1.z), fmaxf(r0.w, r1.w));
  float m10 = fmaxf(fmaxf(r2.x, r3.x), fmaxf(r2.y, r3.y));
  float m11 = fmaxf(fmaxf(r2.z, r3.z), fmaxf(r2.w, r3.w));
  float* pp = p1 + ((size_t)bc * 64 + 2 * i) * 64 + 2 * j;
  pp[0]  = m00; pp[1]  = m01;
  pp[64] = m10; pp[65] = m11;
  p2[(size_t)bc * 1024 + i * 32 + j] = fmaxf(fmaxf(m00, m01), fmaxf(m10, m11));
}

// ---------------------------------------------------------------------------
// Kernels 2-4: depthwise 3x3, stride 1, pad 1
// ---------------------------------------------------------------------------
template <int HS, int WS, int HSH, int WSH>
__global__ __launch_bounds__(256) void dwconv_kernel(const float* __restrict__ in,
                                                     const float* __restrict__ wt,
                                                     const float* __restrict__ bias,
                                                     float* __restrict__ out) {
  int idx = blockIdx.x * 256 + threadIdx.x;
  int w_ = idx & (WS - 1);
  int h_ = (idx >> WSH) & (HS - 1);
  int bc = idx >> (WSH + HSH);
  int c  = bc & (CC - 1);
  const float* ip = in + (size_t)bc * (HS * WS);
  float wv[9];
#pragma unroll
  for (int t = 0; t < 9; ++t) wv[t] = wt[c * 9 + t];
  float acc = bias[c];
#pragma unroll
  for (int dh = 0; dh < 3; ++dh) {
    int hh = h_ + dh - 1;
    if ((unsigned)hh >= (unsigned)HS) continue;
#pragma unroll
    for (int dw = 0; dw < 3; ++dw) {
      int ww = w_ + dw - 1;
      if ((unsigned)ww >= (unsigned)WS) continue;
      acc = fmaf(wv[dh * 3 + dw], ip[hh * WS + ww], acc);
    }
  }
  out[idx] = acc;
}

// ---------------------------------------------------------------------------
// Kernel 5: cooperative attention. Tile = 16w x 2h pixels = 8 2x2-blocks.
// Each 2x2 block shares one k-pixel (c1) and one v-pixel (c2), hence one
// full E[i][j] = exp(v_i k_j)/denom_j matrix -> 4x fewer exps.
// Phase 1: thread (eb,j) computes E column j + denom + scale_p[j]=q_p[j]/denom.
// Phase 2: thread (p,ichunk) does qkv[i] = sum_j E[i][j]*scale_p[j] -> global.
// LDS 38.5 KB -> 4 blocks/CU -> 16 waves/CU.
// ---------------------------------------------------------------------------
__global__ __launch_bounds__(256) void attn_kernel(const float* __restrict__ s0,
                                                   const float* __restrict__ c1,
                                                   const float* __restrict__ c2,
                                                   float* __restrict__ qkv_g) {
  int bid = blockIdx.x;        // 2048 = 4 b * 64 th * 8 tw
  int tw = bid & 7;
  int th = (bid >> 3) & 63;
  int b  = bid >> 9;
  int t  = threadIdx.x;

  __shared__ __align__(16) float vsh[8 * 36];      // [eb][i] pad 36
  __shared__ __align__(16) float Ebuf[8 * 1036];   // [eb]: i*32 + j, eb-stride 1036
  __shared__ float scaleT[32 * 33];                // [j]: *33 + p

  // ---- phase 0: stage v ----
  {
    int eb = t >> 5, i = t & 31;
    int h4 = th >> 1;
    int w4 = tw * 4 + (eb >> 1);
    vsh[eb * 36 + i] = c2[((size_t)(b * CC + i) * 32 + h4) * 32 + w4];
  }
  __syncthreads();

  // ---- phase 1: E columns ----
  {
    int eb = t >> 5, j = t & 31;
    float kj = c1[((size_t)(b * CC + j) * 64 + th) * 64 + (tw * 8 + eb)];
    float vv[32];
    const float4* v4 = (const float4*)(vsh + eb * 36);
#pragma unroll
    for (int iq = 0; iq < 8; ++iq) {
      float4 q_ = v4[iq];
      vv[4 * iq] = q_.x; vv[4 * iq + 1] = q_.y; vv[4 * iq + 2] = q_.z; vv[4 * iq + 3] = q_.w;
    }
    float vmax = vv[0], vmin = vv[0];
#pragma unroll
    for (int i = 1; i < CC; ++i) {
      vmax = fmaxf(vmax, vv[i]);
      vmin = fminf(vmin, vv[i]);
    }
    const float L2E = 1.4426950408889634f;
    float m  = (kj >= 0.f) ? kj * vmax : kj * vmin;
    float kl = kj * L2E;
    float nm = -m * L2E;
    float d0 = 0.f, d1 = 0.f, d2 = 0.f, d3 = 0.f;
    float* Ecol = Ebuf + eb * 1036 + j;
#pragma unroll
    for (int i = 0; i < CC; i += 4) {
      float e0 = __builtin_amdgcn_exp2f(fmaf(vv[i],     kl, nm)); Ecol[i * 32]       = e0; d0 += e0;
      float e1 = __builtin_amdgcn_exp2f(fmaf(vv[i + 1], kl, nm)); Ecol[(i + 1) * 32] = e1; d1 += e1;
      float e2 = __builtin_amdgcn_exp2f(fmaf(vv[i + 2], kl, nm)); Ecol[(i + 2) * 32] = e2; d2 += e2;
      float e3 = __builtin_amdgcn_exp2f(fmaf(vv[i + 3], kl, nm)); Ecol[(i + 3) * 32] = e3; d3 += e3;
    }
    float rd = __fdividef(1.f, (d0 + d1) + (d2 + d3));
    int h0 = th * 2, w0 = tw * 16;
    size_t qb = ((size_t)(b * CC + j) * HH + h0) * WW + w0 + eb * 2;
#pragma unroll
    for (int px = 0; px < 4; ++px) {
      int hh = px >> 1, wwb = px & 1;
      float q = s0[qb + hh * WW + wwb];
      scaleT[j * 33 + (hh * 16 + eb * 2 + wwb)] = q * rd;
    }
  }
  __syncthreads();

  // ---- phase 2: qkv matvec ----
  {
    int p = t & 31, ic = t >> 5;        // p = hh*16+ww, ic = i-chunk (4 i's)
    int eb = (p & 15) >> 1;
    const float* Er = Ebuf + eb * 1036 + ic * 128;   // rows ic*4 .. ic*4+3
    float a0 = 0.f, a1 = 0.f, a2 = 0.f, a3 = 0.f;
#pragma unroll
    for (int jq = 0; jq < 8; ++jq) {
      float4 e0 = *(const float4*)(Er + jq * 4);
      float4 e1 = *(const float4*)(Er + 32 + jq * 4);
      float4 e2 = *(const float4*)(Er + 64 + jq * 4);
      float4 e3 = *(const float4*)(Er + 96 + jq * 4);
      float s0v = scaleT[(jq * 4)     * 33 + p];
      float s1v = scaleT[(jq * 4 + 1) * 33 + p];
      float s2v = scaleT[(jq * 4 + 2) * 33 + p];
      float s3v = scaleT[(jq * 4 + 3) * 33 + p];
      a0 = fmaf(e0.x, s0v, fmaf(e0.y, s1v, fmaf(e0.z, s2v, fmaf(e0.w, s3v, a0))));
      a1 = fmaf(e1.x, s0v, fmaf(e1.y, s1v, fmaf(e1.z, s2v, fmaf(e1.w, s3v, a1))));
      a2 = fmaf(e2.x, s0v, fmaf(e2.y, s1v, fmaf(e2.z, s2v, fmaf(e2.w, s3v, a2))));
      a3 = fmaf(e3.x, s0v, fmaf(e3.y, s1v, fmaf(e3.z, s2v, fmaf(e3.w, s3v, a3))));
    }
    int hh = p >> 4, ww = p & 15;
    int n = ((b * HH + th * 2 + hh) * WW + tw * 16 + ww);   // global pixel id
    int i0 = ic * 4;
    qkv_g[(size_t)(i0 + 0) * 65536 + n] = a0;
    qkv_g[(size_t)(i0 + 1) * 65536 + n] = a1;
    qkv_g[(size_t)(i0 + 2) * 65536 + n] = a2;
    qkv_g[(size_t)(i0 + 3) * 65536 + n] = a3;
  }
}

// ---------------------------------------------------------------------------
// Kernel 6: epilogue: out = gelu(wa @ qkv + ba) * x. One thread per pixel.
// wa/ba wave-uniform -> scalar s_loads. 4-way o-chunks for ILP.
// ---------------------------------------------------------------------------
__global__ __launch_bounds__(256) void epi_kernel(const float* __restrict__ qkv_g,
                                                  const float* __restrict__ x,
                                                  const float* __restrict__ wa,
                                                  const float* __restrict__ ba,
                                                  float* __restrict__ out) {
  int n = blockIdx.x * 256 + threadIdx.x;    // 65536 pixels
  float qkv[CC];
#pragma unroll
  for (int i = 0; i < CC; ++i) qkv[i] = qkv_g[(size_t)i * 65536 + n];
  int bo = (n >> 14) * CC;
  int hw = n & 16383;
  for (int ob = 0; ob < CC; ob += 4) {
    float y0 = ba[ob], y1 = ba[ob + 1], y2 = ba[ob + 2], y3 = ba[ob + 3];
#pragma unroll
    for (int i = 0; i < CC; ++i) {
      float qv = qkv[i];
      y0 = fmaf(wa[(ob)     * CC + i], qv, y0);
      y1 = fmaf(wa[(ob + 1) * CC + i], qv, y1);
      y2 = fmaf(wa[(ob + 2) * CC + i], qv, y2);
      y3 = fmaf(wa[(ob + 3) * CC + i], qv, y3);
    }
    const float RS2 = 0.70710678118654752f;
    float g0 = 0.5f * y0 * (1.f + erff(y0 * RS2));
    float g1 = 0.5f * y1 * (1.f + erff(y1 * RS2));
    float g2 = 0.5f * y2 * (1.f + erff(y2 * RS2));
    float g3 = 0.5f * y3 * (1.f + erff(y3 * RS2));
    size_t oi0 = (size_t)(bo + ob) * 16384 + hw;
    out[oi0]           = g0 * x[oi0];
    out[oi0 + 16384]   = g1 * x[oi0 + 16384];
    out[oi0 + 32768]   = g2 * x[oi0 + 32768];
    out[oi0 + 49152]   = g3 * x[oi0 + 49152];
  }
}

// ---------------------------------------------------------------------------
extern "C" void kernel_launch(void* const* d_in, const int* in_sizes, int n_in,
                              void* d_out, int out_size, void* d_ws, size_t ws_size,
                              hipStream_t stream) {
  const float* x  = (const float*)d_in[0];
  const float* w0 = (const float*)d_in[1];
  const float* b0 = (const float*)d_in[2];
  const float* w1 = (const float*)d_in[3];
  const float* b1 = (const float*)d_in[4];
  const float* w2 = (const float*)d_in[5];
  const float* b2 = (const float*)d_in[6];
  const float* wa = (const float*)d_in[7];
  const float* ba = (const float*)d_in[8];
  float* out = (float*)d_out;

  float* ws = (float*)d_ws;
  float* s0 = ws;                    // 2097152
  float* p1 = s0 + 2097152;          //  524288
  float* c1 = p1 + 524288;           //  524288
  float* p2 = c1 + 524288;           //  131072
  float* c2 = p2 + 131072;           //  131072
  float* qkv_g = c2 + 131072;        // 2097152  (layout [i][pixel])

  pool_kernel<<<512, 256, 0, stream>>>(x, p1, p2);
  dwconv_kernel<128, 128, 7, 7><<<8192, 256, 0, stream>>>(x, w0, b0, s0);
  dwconv_kernel<64, 64, 6, 6><<<2048, 256, 0, stream>>>(p1, w1, b1, c1);
  dwconv_kernel<32, 32, 5, 5><<<512, 256, 0, stream>>>(p2, w2, b2, c2);
  attn_kernel<<<2048, 256, 0, stream>>>(s0, c1, c2, qkv_g);
  epi_kernel<<<256, 256, 0, stream>>>(qkv_g, x, wa, ba, out);
}

// Round 3
// 121.681 us; speedup vs baseline: 1.0994x; 1.0994x over previous
//
#include <hip/hip_runtime.h>
#include <math.h>

#define BB 4
#define CC 32
#define HH 128
#define WW 128

// ---------------------------------------------------------------------------
// Pool body: x (B,C,128,128) NCHW -> p1 (B,C,64,64), p2 (B,C,32,32) NCHW.
// One thread per p2 element; 4x4 patch via 4x float4.
// ---------------------------------------------------------------------------
__device__ __forceinline__ void pool_body(int bid, const float* __restrict__ x,
                                          float* __restrict__ p1,
                                          float* __restrict__ p2) {
  int idx = bid * 256 + threadIdx.x;                 // B*C*32*32 = 131072
  int j  = idx & 31;
  int i  = (idx >> 5) & 31;
  int bc = idx >> 10;
  const float* xp = x + ((size_t)bc * HH + 4 * i) * WW + 4 * j;
  float4 r0 = *(const float4*)(xp);
  float4 r1 = *(const float4*)(xp + WW);
  float4 r2 = *(const float4*)(xp + 2 * WW);
  float4 r3 = *(const float4*)(xp + 3 * WW);
  float m00 = fmaxf(fmaxf(r0.x, r1.x), fmaxf(r0.y, r1.y));
  float m01 = fmaxf(fmaxf(r0.z, r1.z), fmaxf(r0.w, r1.w));
  float m10 = fmaxf(fmaxf(r2.x, r3.x), fmaxf(r2.y, r3.y));
  float m11 = fmaxf(fmaxf(r2.z, r3.z), fmaxf(r2.w, r3.w));
  float* pp = p1 + ((size_t)bc * 64 + 2 * i) * 64 + 2 * j;
  pp[0]  = m00; pp[1]  = m01;
  pp[64] = m10; pp[65] = m11;
  p2[(size_t)bc * 1024 + i * 32 + j] = fmaxf(fmaxf(m00, m01), fmaxf(m10, m11));
}

// ---------------------------------------------------------------------------
// Depthwise 3x3 (stride 1, zero-pad 1), NCHW in -> NHWC out (LDS transpose).
// Block = one (b,h) row x 32-wide w segment x all 32 channels.
// Thread (c = t>>3, pq = t&7) computes 4 outputs (w = wseg*32+pq*4 ..+3).
// Reads coalesced (8 lanes x float4 = 128B per channel row); NHWC write is
// exactly lane-contiguous (thread t writes bytes [t*16, t*16+16)).
// ---------------------------------------------------------------------------
template <int HS, int WS>
__device__ __forceinline__ void dwconv_nhwc_body(int bid,
                                                 const float* __restrict__ in,
                                                 const float* __restrict__ wt,
                                                 const float* __restrict__ bias,
                                                 float* __restrict__ outt) {
  constexpr int WSEG = WS / 32;
  int t = threadIdx.x;
  int wseg = bid % WSEG;
  int h = (bid / WSEG) % HS;
  int b = bid / (WSEG * HS);
  int c = t >> 3, pq = t & 7;
  int w0 = wseg * 32 + pq * 4;
  const float* ip = in + (size_t)(b * CC + c) * (HS * WS);
  float wv[9];
#pragma unroll
  for (int k = 0; k < 9; ++k) wv[k] = wt[c * 9 + k];
  float bz = bias[c];
  float acc0 = bz, acc1 = bz, acc2 = bz, acc3 = bz;
#pragma unroll
  for (int dh = -1; dh <= 1; ++dh) {
    int hh = h + dh;
    if ((unsigned)hh >= (unsigned)HS) continue;
    const float* rp = ip + hh * WS + w0;
    float l  = (w0 > 0)      ? rp[-1] : 0.f;
    float4 m = *(const float4*)rp;
    float r  = (w0 + 4 < WS) ? rp[4]  : 0.f;
    float wA = wv[(dh + 1) * 3], wB = wv[(dh + 1) * 3 + 1], wC = wv[(dh + 1) * 3 + 2];
    acc0 = fmaf(wA, l,   fmaf(wB, m.x, fmaf(wC, m.y, acc0)));
    acc1 = fmaf(wA, m.x, fmaf(wB, m.y, fmaf(wC, m.z, acc1)));
    acc2 = fmaf(wA, m.y, fmaf(wB, m.z, fmaf(wC, m.w, acc2)));
    acc3 = fmaf(wA, m.z, fmaf(wB, m.w, fmaf(wC, r,   acc3)));
  }
  __shared__ float tile[32][33];
  tile[pq * 4 + 0][c] = acc0;
  tile[pq * 4 + 1][c] = acc1;
  tile[pq * 4 + 2][c] = acc2;
  tile[pq * 4 + 3][c] = acc3;
  __syncthreads();
  int p = t >> 3, c4 = (t & 7) * 4;
  float4 v = *(const float4*)&tile[p][c4];
  float* op = outt + ((size_t)(b * HS + h) * WS + wseg * 32 + p) * 32 + c4;
  *(float4*)op = v;
}

// Kernel A: pool (blocks 0..511) + dwconv128 (blocks 512..2559). Both read x.
__global__ __launch_bounds__(256) void kernelA(const float* __restrict__ x,
                                               const float* __restrict__ w0,
                                               const float* __restrict__ b0,
                                               float* __restrict__ p1,
                                               float* __restrict__ p2,
                                               float* __restrict__ s0t) {
  if (blockIdx.x < 512) pool_body(blockIdx.x, x, p1, p2);
  else dwconv_nhwc_body<128, 128>(blockIdx.x - 512, x, w0, b0, s0t);
}

// Kernel B: dwconv64 (blocks 0..511) + dwconv32 (blocks 512..639).
__global__ __launch_bounds__(256) void kernelB(const float* __restrict__ p1,
                                               const float* __restrict__ w1,
                                               const float* __restrict__ b1,
                                               const float* __restrict__ p2,
                                               const float* __restrict__ w2,
                                               const float* __restrict__ b2,
                                               float* __restrict__ c1t,
                                               float* __restrict__ c2t) {
  if (blockIdx.x < 512) dwconv_nhwc_body<64, 64>(blockIdx.x, p1, w1, b1, c1t);
  else dwconv_nhwc_body<32, 32>(blockIdx.x - 512, p2, w2, b2, c2t);
}

// ---------------------------------------------------------------------------
// Kernel C: cooperative attention. Tile = 16w x 2h pixels = 8 2x2-blocks.
// All q/k/v loads now NHWC -> lane-contiguous (channel is lane-minor).
// ---------------------------------------------------------------------------
__global__ __launch_bounds__(256) void attn_kernel(const float* __restrict__ s0t,
                                                   const float* __restrict__ c1t,
                                                   const float* __restrict__ c2t,
                                                   float* __restrict__ qkv_g) {
  int bid = blockIdx.x;        // 2048 = 4 b * 64 th * 8 tw
  int tw = bid & 7;
  int th = (bid >> 3) & 63;
  int b  = bid >> 9;
  int t  = threadIdx.x;

  __shared__ __align__(16) float vsh[8 * 36];      // [eb][i]
  __shared__ __align__(16) float Ebuf[8 * 1036];   // [eb]: i*32 + j
  __shared__ float scaleT[32 * 33];                // [j]: *33 + p

  // ---- phase 0: stage v (coalesced: i lane-minor) ----
  {
    int eb = t >> 5, i = t & 31;
    int h4 = th >> 1;
    int w4 = tw * 4 + (eb >> 1);
    vsh[eb * 36 + i] = c2t[((size_t)(b * 32 + h4) * 32 + w4) * 32 + i];
  }
  __syncthreads();

  // ---- phase 1: E columns ----
  {
    int eb = t >> 5, j = t & 31;
    float kj = c1t[((size_t)(b * 64 + th) * 64 + (tw * 8 + eb)) * 32 + j];
    float vv[32];
    const float4* v4 = (const float4*)(vsh + eb * 36);
#pragma unroll
    for (int iq = 0; iq < 8; ++iq) {
      float4 q_ = v4[iq];
      vv[4 * iq] = q_.x; vv[4 * iq + 1] = q_.y; vv[4 * iq + 2] = q_.z; vv[4 * iq + 3] = q_.w;
    }
    float vmax = vv[0], vmin = vv[0];
#pragma unroll
    for (int i = 1; i < CC; ++i) {
      vmax = fmaxf(vmax, vv[i]);
      vmin = fminf(vmin, vv[i]);
    }
    const float L2E = 1.4426950408889634f;
    float m  = (kj >= 0.f) ? kj * vmax : kj * vmin;
    float kl = kj * L2E;
    float nm = -m * L2E;
    float d0 = 0.f, d1 = 0.f, d2 = 0.f, d3 = 0.f;
    float* Ecol = Ebuf + eb * 1036 + j;
#pragma unroll
    for (int i = 0; i < CC; i += 4) {
      float e0 = __builtin_amdgcn_exp2f(fmaf(vv[i],     kl, nm)); Ecol[i * 32]       = e0; d0 += e0;
      float e1 = __builtin_amdgcn_exp2f(fmaf(vv[i + 1], kl, nm)); Ecol[(i + 1) * 32] = e1; d1 += e1;
      float e2 = __builtin_amdgcn_exp2f(fmaf(vv[i + 2], kl, nm)); Ecol[(i + 2) * 32] = e2; d2 += e2;
      float e3 = __builtin_amdgcn_exp2f(fmaf(vv[i + 3], kl, nm)); Ecol[(i + 3) * 32] = e3; d3 += e3;
    }
    float rd = __fdividef(1.f, (d0 + d1) + (d2 + d3));
    // q: 4 pixels of the 2x2 block, NHWC -> j lane-minor, coalesced
    size_t qb = ((size_t)(b * HH + th * 2) * WW + tw * 16 + eb * 2) * 32 + j;
#pragma unroll
    for (int px = 0; px < 4; ++px) {
      int hh = px >> 1, wwb = px & 1;
      float q = s0t[qb + (size_t)(hh * WW + wwb) * 32];
      scaleT[j * 33 + (hh * 16 + eb * 2 + wwb)] = q * rd;
    }
  }
  __syncthreads();

  // ---- phase 2: qkv matvec ----
  {
    int p = t & 31, ic = t >> 5;
    int eb = (p & 15) >> 1;
    const float* Er = Ebuf + eb * 1036 + ic * 128;
    float a0 = 0.f, a1 = 0.f, a2 = 0.f, a3 = 0.f;
#pragma unroll
    for (int jq = 0; jq < 8; ++jq) {
      float4 e0 = *(const float4*)(Er + jq * 4);
      float4 e1 = *(const float4*)(Er + 32 + jq * 4);
      float4 e2 = *(const float4*)(Er + 64 + jq * 4);
      float4 e3 = *(const float4*)(Er + 96 + jq * 4);
      float s0v = scaleT[(jq * 4)     * 33 + p];
      float s1v = scaleT[(jq * 4 + 1) * 33 + p];
      float s2v = scaleT[(jq * 4 + 2) * 33 + p];
      float s3v = scaleT[(jq * 4 + 3) * 33 + p];
      a0 = fmaf(e0.x, s0v, fmaf(e0.y, s1v, fmaf(e0.z, s2v, fmaf(e0.w, s3v, a0))));
      a1 = fmaf(e1.x, s0v, fmaf(e1.y, s1v, fmaf(e1.z, s2v, fmaf(e1.w, s3v, a1))));
      a2 = fmaf(e2.x, s0v, fmaf(e2.y, s1v, fmaf(e2.z, s2v, fmaf(e2.w, s3v, a2))));
      a3 = fmaf(e3.x, s0v, fmaf(e3.y, s1v, fmaf(e3.z, s2v, fmaf(e3.w, s3v, a3))));
    }
    int hh = p >> 4, ww = p & 15;
    int n = ((b * HH + th * 2 + hh) * WW + tw * 16 + ww);
    int i0 = ic * 4;
    qkv_g[(size_t)(i0 + 0) * 65536 + n] = a0;
    qkv_g[(size_t)(i0 + 1) * 65536 + n] = a1;
    qkv_g[(size_t)(i0 + 2) * 65536 + n] = a2;
    qkv_g[(size_t)(i0 + 3) * 65536 + n] = a3;
  }
}

// ---------------------------------------------------------------------------
// Kernel D: epilogue: out = gelu(wa @ qkv + ba) * x. One thread per pixel.
// ---------------------------------------------------------------------------
__global__ __launch_bounds__(256) void epi_kernel(const float* __restrict__ qkv_g,
                                                  const float* __restrict__ x,
                                                  const float* __restrict__ wa,
                                                  const float* __restrict__ ba,
                                                  float* __restrict__ out) {
  int n = blockIdx.x * 256 + threadIdx.x;
  float qkv[CC];
#pragma unroll
  for (int i = 0; i < CC; ++i) qkv[i] = qkv_g[(size_t)i * 65536 + n];
  int bo = (n >> 14) * CC;
  int hw = n & 16383;
  for (int ob = 0; ob < CC; ob += 4) {
    float y0 = ba[ob], y1 = ba[ob + 1], y2 = ba[ob + 2], y3 = ba[ob + 3];
#pragma unroll
    for (int i = 0; i < CC; ++i) {
      float qv = qkv[i];
      y0 = fmaf(wa[(ob)     * CC + i], qv, y0);
      y1 = fmaf(wa[(ob + 1) * CC + i], qv, y1);
      y2 = fmaf(wa[(ob + 2) * CC + i], qv, y2);
      y3 = fmaf(wa[(ob + 3) * CC + i], qv, y3);
    }
    const float RS2 = 0.70710678118654752f;
    float g0 = 0.5f * y0 * (1.f + erff(y0 * RS2));
    float g1 = 0.5f * y1 * (1.f + erff(y1 * RS2));
    float g2 = 0.5f * y2 * (1.f + erff(y2 * RS2));
    float g3 = 0.5f * y3 * (1.f + erff(y3 * RS2));
    size_t oi0 = (size_t)(bo + ob) * 16384 + hw;
    out[oi0]         = g0 * x[oi0];
    out[oi0 + 16384] = g1 * x[oi0 + 16384];
    out[oi0 + 32768] = g2 * x[oi0 + 32768];
    out[oi0 + 49152] = g3 * x[oi0 + 49152];
  }
}

// ---------------------------------------------------------------------------
extern "C" void kernel_launch(void* const* d_in, const int* in_sizes, int n_in,
                              void* d_out, int out_size, void* d_ws, size_t ws_size,
                              hipStream_t stream) {
  const float* x  = (const float*)d_in[0];
  const float* w0 = (const float*)d_in[1];
  const float* b0 = (const float*)d_in[2];
  const float* w1 = (const float*)d_in[3];
  const float* b1 = (const float*)d_in[4];
  const float* w2 = (const float*)d_in[5];
  const float* b2 = (const float*)d_in[6];
  const float* wa = (const float*)d_in[7];
  const float* ba = (const float*)d_in[8];
  float* out = (float*)d_out;

  float* ws = (float*)d_ws;
  float* s0t = ws;                   // 2097152  NHWC
  float* p1  = s0t + 2097152;        //  524288  NCHW
  float* c1t = p1 + 524288;          //  524288  NHWC
  float* p2  = c1t + 524288;         //  131072  NCHW
  float* c2t = p2 + 131072;          //  131072  NHWC
  float* qkv_g = c2t + 131072;       // 2097152  [i][pixel]

  kernelA<<<2560, 256, 0, stream>>>(x, w0, b0, p1, p2, s0t);
  kernelB<<<640, 256, 0, stream>>>(p1, w1, b1, p2, w2, b2, c1t, c2t);
  attn_kernel<<<2048, 256, 0, stream>>>(s0t, c1t, c2t, qkv_g);
  epi_kernel<<<256, 256, 0, stream>>>(qkv_g, x, wa, ba, out);
}

// Round 4
// 120.496 us; speedup vs baseline: 1.1102x; 1.0098x over previous
//
#include <hip/hip_runtime.h>
#include <math.h>

#define CC 32

// ---------------------------------------------------------------------------
// Fully-fused SAFM: pool + 3 depthwise convs + shared-E softmax mixing +
// 1x1 conv + exact GELU + mul-x, ONE kernel, no global intermediates.
//
// Block = 16w x 2h pixel tile (8 2x2-blocks "eb"), grid 2048 = 4b*64th*8tw.
// Each 2x2 block shares one k-pixel (c1, half res) and one v-pixel (c2,
// quarter res) => one E[i][j]=exp(v_i k_j)/denom_j matrix per eb (4x fewer
// exps), only q differs per pixel.
//
// LDS (55.4 KB, 2 blocks/CU):
//   region A (overlaid):  S1-S3: xs[32][12][25] + p1s[32][3][13] + p2s[32][3][7]
//                         S4-S5: Ebuf[8][1036] + scT[32][33]
//   region B (persistent): s0s[32px][33], c1s[8][33], vsh[8][36], qkvs[32px][33]
// ---------------------------------------------------------------------------
__global__ __launch_bounds__(256, 2) void fused_safm(
    const float* __restrict__ x,
    const float* __restrict__ w0, const float* __restrict__ b0,
    const float* __restrict__ w1, const float* __restrict__ b1,
    const float* __restrict__ w2, const float* __restrict__ b2,
    const float* __restrict__ wa, const float* __restrict__ ba,
    float* __restrict__ out) {
  int bid = blockIdx.x;
  int tw = bid & 7;
  int th = (bid >> 3) & 63;
  int b  = bid >> 9;
  int t  = threadIdx.x;
  int h4  = th >> 1;          // quarter-res row of this tile
  int dth = (th & 1) * 2;     // tile row offset inside the 4-row x window
  int R0 = 4 * h4 - 4;        // x window top row (12 rows)
  int C0 = 16 * tw - 4;       // x window left col (24 cols)

  __shared__ __align__(16) float smA[11520];   // 46080 B, overlaid region
  float* xs   = smA;                           // [c][r][col] c*300+r*25+col
  float* p1s  = smA + 9600;                    // [c][hp][wp] c*39+hp*13+wp
  float* p2s  = smA + 10848;                   // [c][hq][wq] c*21+hq*7+wq
  float* Ebuf = smA;                           // [eb]: i*32+j, eb stride 1036
  float* scT  = smA + 8288;                    // [j]: j*33+p
  __shared__ __align__(16) float s0s[1056];    // [p][c] p*33+c
  __shared__ __align__(16) float c1s[264];     // [eb][j] eb*33+j
  __shared__ __align__(16) float vsh[288];     // [eb][i] eb*36+i
  __shared__ __align__(16) float qkvs[1056];   // [p][i] p*33+i

  // ---- S1: stage x window (zero-filled OOB => free zero-padding) ----
  {
    int c = t >> 3, sub = t & 7;
    const float* xc = x + ((size_t)(b * CC + c) << 14);
    float* xd = xs + c * 300;
#pragma unroll
    for (int r = 0; r < 12; ++r) {
      int row = R0 + r;
      bool rok = (unsigned)row < 128u;
#pragma unroll
      for (int m = 0; m < 3; ++m) {
        int col = sub * 3 + m;
        int gcol = C0 + col;
        float v = 0.f;
        if (rok && (unsigned)gcol < 128u) v = xc[row * 128 + gcol];
        xd[r * 25 + col] = v;
      }
    }
  }
  __syncthreads();

  // ---- S2: pooled tiles p1 (10x3 per ch), p2 (6x3 per ch), OOB cells = 0 ----
  for (int k = 0; k < 4; ++k) {
    int idx = t + k * 256;
    if (idx < 960) {
      int c = idx / 30, rem = idx % 30;
      int hp = rem / 10, wp = rem % 10;
      int prow = th - 1 + hp, pcol = 8 * tw - 1 + wp;
      float v = 0.f;
      if ((unsigned)prow < 64u && (unsigned)pcol < 64u) {
        const float* xp = xs + c * 300 + (dth + 2 * hp + 2) * 25 + (2 * wp + 2);
        v = fmaxf(fmaxf(xp[0], xp[1]), fmaxf(xp[25], xp[26]));
      }
      p1s[c * 39 + hp * 13 + wp] = v;
    }
  }
  for (int k = 0; k < 3; ++k) {
    int idx = t + k * 256;
    if (idx < 576) {
      int c = idx / 18, rem = idx % 18;
      int hq = rem / 6, wq = rem % 6;
      int prow = h4 - 1 + hq, pcol = 4 * tw - 1 + wq;
      float v = 0.f;
      if ((unsigned)prow < 32u && (unsigned)pcol < 32u) {
        const float* xp = xs + c * 300 + (4 * hq) * 25 + 4 * wq;
        float m0 = fmaxf(fmaxf(xp[0],  xp[1]),  fmaxf(xp[2],  xp[3]));
        float m1 = fmaxf(fmaxf(xp[25], xp[26]), fmaxf(xp[27], xp[28]));
        float m2 = fmaxf(fmaxf(xp[50], xp[51]), fmaxf(xp[52], xp[53]));
        float m3 = fmaxf(fmaxf(xp[75], xp[76]), fmaxf(xp[77], xp[78]));
        v = fmaxf(fmaxf(m0, m1), fmaxf(m2, m3));
      }
      p2s[c * 21 + hq * 7 + wq] = v;
    }
  }
  __syncthreads();

  // ---- S3: the three depthwise 3x3 convs, all from LDS ----
  {
    // s0: 4 pixels per thread (c = t>>3, gg = t&7)
    int c = t >> 3, gg = t & 7;
    const float* wc = w0 + c * 9;
    float wv[9];
#pragma unroll
    for (int q = 0; q < 9; ++q) wv[q] = wc[q];
    float bz = b0[c];
    int hh = gg >> 2, wb = (gg & 3) * 4;
#pragma unroll
    for (int k = 0; k < 4; ++k) {
      int ww = wb + k;
      const float* xp = xs + c * 300 + (dth + hh + 3) * 25 + (ww + 3);
      float acc = bz;
      acc = fmaf(wv[0], xp[0],  fmaf(wv[1], xp[1],  fmaf(wv[2], xp[2],  acc)));
      acc = fmaf(wv[3], xp[25], fmaf(wv[4], xp[26], fmaf(wv[5], xp[27], acc)));
      acc = fmaf(wv[6], xp[50], fmaf(wv[7], xp[51], fmaf(wv[8], xp[52], acc)));
      s0s[(hh * 16 + ww) * 33 + c] = acc;
    }
  }
  {
    // c1 (k) and c2->vsh (v): one each per thread (eb = t>>5, j = t&31)
    int eb = t >> 5, j = t & 31;
    {
      const float* wc = w1 + j * 9;
      const float* pp = p1s + j * 39 + eb;      // center wp = eb+1
      float acc = b1[j];
      acc = fmaf(wc[0], pp[0],  fmaf(wc[1], pp[1],  fmaf(wc[2], pp[2],  acc)));
      acc = fmaf(wc[3], pp[13], fmaf(wc[4], pp[14], fmaf(wc[5], pp[15], acc)));
      acc = fmaf(wc[6], pp[26], fmaf(wc[7], pp[27], fmaf(wc[8], pp[28], acc)));
      c1s[eb * 33 + j] = acc;
    }
    {
      const float* wc = w2 + j * 9;
      const float* pp = p2s + j * 21 + (eb >> 1);  // center wq = (eb>>1)+1
      float acc = b2[j];
      acc = fmaf(wc[0], pp[0],  fmaf(wc[1], pp[1],  fmaf(wc[2], pp[2],  acc)));
      acc = fmaf(wc[3], pp[7],  fmaf(wc[4], pp[8],  fmaf(wc[5], pp[9],  acc)));
      acc = fmaf(wc[6], pp[14], fmaf(wc[7], pp[15], fmaf(wc[8], pp[16], acc)));
      vsh[eb * 36 + j] = acc;
    }
  }
  __syncthreads();   // after this, xs/p1s/p2s are dead; Ebuf/scT take over

  // ---- S4: E columns + per-pixel scale = q/denom ----
  {
    int eb = t >> 5, j = t & 31;
    float kj = c1s[eb * 33 + j];
    float vv[32];
    const float4* v4 = (const float4*)(vsh + eb * 36);
#pragma unroll
    for (int iq = 0; iq < 8; ++iq) {
      float4 q_ = v4[iq];
      vv[4 * iq] = q_.x; vv[4 * iq + 1] = q_.y; vv[4 * iq + 2] = q_.z; vv[4 * iq + 3] = q_.w;
    }
    float vmax = vv[0], vmin = vv[0];
#pragma unroll
    for (int i = 1; i < CC; ++i) {
      vmax = fmaxf(vmax, vv[i]);
      vmin = fminf(vmin, vv[i]);
    }
    const float L2E = 1.4426950408889634f;
    float m  = (kj >= 0.f) ? kj * vmax : kj * vmin;   // max_i v[i]*kj
    float kl = kj * L2E;
    float nm = -m * L2E;
    float d0 = 0.f, d1 = 0.f, d2 = 0.f, d3 = 0.f;
    float* Ecol = Ebuf + eb * 1036 + j;
#pragma unroll
    for (int i = 0; i < CC; i += 4) {
      float e0 = __builtin_amdgcn_exp2f(fmaf(vv[i],     kl, nm)); Ecol[i * 32]       = e0; d0 += e0;
      float e1 = __builtin_amdgcn_exp2f(fmaf(vv[i + 1], kl, nm)); Ecol[(i + 1) * 32] = e1; d1 += e1;
      float e2 = __builtin_amdgcn_exp2f(fmaf(vv[i + 2], kl, nm)); Ecol[(i + 2) * 32] = e2; d2 += e2;
      float e3 = __builtin_amdgcn_exp2f(fmaf(vv[i + 3], kl, nm)); Ecol[(i + 3) * 32] = e3; d3 += e3;
    }
    float rd = __fdividef(1.f, (d0 + d1) + (d2 + d3));
#pragma unroll
    for (int px = 0; px < 4; ++px) {
      int hh = px >> 1, wwb = px & 1;
      int p = hh * 16 + eb * 2 + wwb;
      scT[j * 33 + p] = s0s[p * 33 + j] * rd;
    }
  }
  __syncthreads();

  // ---- S5: qkv matvec from E ----
  {
    int p = t & 31, ic = t >> 5;
    int eb = (p & 15) >> 1;
    const float* Er = Ebuf + eb * 1036 + ic * 128;
    float a0 = 0.f, a1 = 0.f, a2 = 0.f, a3 = 0.f;
#pragma unroll
    for (int jq = 0; jq < 8; ++jq) {
      float4 e0 = *(const float4*)(Er + jq * 4);
      float4 e1 = *(const float4*)(Er + 32 + jq * 4);
      float4 e2 = *(const float4*)(Er + 64 + jq * 4);
      float4 e3 = *(const float4*)(Er + 96 + jq * 4);
      float s0v = scT[(jq * 4)     * 33 + p];
      float s1v = scT[(jq * 4 + 1) * 33 + p];
      float s2v = scT[(jq * 4 + 2) * 33 + p];
      float s3v = scT[(jq * 4 + 3) * 33 + p];
      a0 = fmaf(e0.x, s0v, fmaf(e0.y, s1v, fmaf(e0.z, s2v, fmaf(e0.w, s3v, a0))));
      a1 = fmaf(e1.x, s0v, fmaf(e1.y, s1v, fmaf(e1.z, s2v, fmaf(e1.w, s3v, a1))));
      a2 = fmaf(e2.x, s0v, fmaf(e2.y, s1v, fmaf(e2.z, s2v, fmaf(e2.w, s3v, a2))));
      a3 = fmaf(e3.x, s0v, fmaf(e3.y, s1v, fmaf(e3.z, s2v, fmaf(e3.w, s3v, a3))));
    }
    int i0 = ic * 4;
    qkvs[p * 33 + i0]     = a0;
    qkvs[p * 33 + i0 + 1] = a1;
    qkvs[p * 33 + i0 + 2] = a2;
    qkvs[p * 33 + i0 + 3] = a3;
  }
  __syncthreads();

  // ---- S6: 1x1 conv + exact GELU + mul x, float4 store ----
  {
    int o = t >> 3, g = t & 7;
    int hh = g >> 2, wb = (g & 3) * 4;
    const float* wo = wa + o * 32;
    const float* q0 = qkvs + (hh * 16 + wb)     * 33;
    const float* q1 = qkvs + (hh * 16 + wb + 1) * 33;
    const float* q2 = qkvs + (hh * 16 + wb + 2) * 33;
    const float* q3 = qkvs + (hh * 16 + wb + 3) * 33;
    float bz = ba[o];
    float y0 = bz, y1 = bz, y2 = bz, y3 = bz;
#pragma unroll
    for (int i = 0; i < 32; ++i) {
      float w = wo[i];
      y0 = fmaf(w, q0[i], y0);
      y1 = fmaf(w, q1[i], y1);
      y2 = fmaf(w, q2[i], y2);
      y3 = fmaf(w, q3[i], y3);
    }
    const float RS2 = 0.70710678118654752f;
    float g0 = 0.5f * y0 * (1.f + erff(y0 * RS2));
    float g1 = 0.5f * y1 * (1.f + erff(y1 * RS2));
    float g2 = 0.5f * y2 * (1.f + erff(y2 * RS2));
    float g3 = 0.5f * y3 * (1.f + erff(y3 * RS2));
    size_t ob = (((size_t)(b * CC + o) * 128) + (2 * th + hh)) * 128 + 16 * tw + wb;
    float4 xv = *(const float4*)(x + ob);
    float4 r;
    r.x = g0 * xv.x; r.y = g1 * xv.y; r.z = g2 * xv.z; r.w = g3 * xv.w;
    *(float4*)(out + ob) = r;
  }
}

// ---------------------------------------------------------------------------
extern "C" void kernel_launch(void* const* d_in, const int* in_sizes, int n_in,
                              void* d_out, int out_size, void* d_ws, size_t ws_size,
                              hipStream_t stream) {
  const float* x  = (const float*)d_in[0];
  const float* w0 = (const float*)d_in[1];
  const float* b0 = (const float*)d_in[2];
  const float* w1 = (const float*)d_in[3];
  const float* b1 = (const float*)d_in[4];
  const float* w2 = (const float*)d_in[5];
  const float* b2 = (const float*)d_in[6];
  const float* wa = (const float*)d_in[7];
  const float* ba = (const float*)d_in[8];
  float* out = (float*)d_out;

  fused_safm<<<2048, 256, 0, stream>>>(x, w0, b0, w1, b1, w2, b2, wa, ba, out);
}